// Round 1
// baseline (87.962 us; speedup 1.0000x reference)
//
#include <hip/hip_runtime.h>
#include <float.h>
#include <limits.h>

#define DECAY 0.7f
#define THETA 1.0f
#define KWIN 5
#define GAIN_UP 1.5f
#define GAIN_DOWN 0.6f

// Replay the LIF recurrence for one vocab entry: n visits starting at v0.
// Matches reference fp32 arithmetic exactly (no fma contraction).
__device__ __forceinline__ void lif_replay(float v0, int n, float& v_out, int& spikes_out) {
    float v = v0;
    int s = 0;
    for (int i = 0; i < n; ++i) {
        float vn = __fadd_rn(__fmul_rn(DECAY, v), 1.0f);
        if (vn >= THETA) { v = __fsub_rn(vn, THETA); ++s; }
        else             { v = vn; }
    }
    v_out = v;
    spikes_out = s;
}

__global__ void hist_kernel(const int* __restrict__ tok, int n, int vocab,
                            int* __restrict__ counts) {
    int i = blockIdx.x * blockDim.x + threadIdx.x;
    if (i < n) {
        int t = tok[i];
        t = t < 0 ? 0 : (t > vocab - 1 ? vocab - 1 : t);
        atomicAdd(&counts[t], 1);
    }
}

// Per vocab entry: replay recurrence, write preliminary gains, and emit this
// block's top-5 (value, index) candidates with lowest-index tie-break.
__global__ void gains_top5_block(const int* __restrict__ counts,
                                 const float* __restrict__ v0,
                                 int vocab,
                                 float* __restrict__ out,
                                 float* __restrict__ cand_v,
                                 int* __restrict__ cand_i) {
    __shared__ float sv[256];
    __shared__ int   si[256];
    __shared__ float rv[256];
    __shared__ int   ri[256];

    int tid = threadIdx.x;
    int t = blockIdx.x * 256 + tid;

    float vfin = -FLT_MAX;
    int   idx  = INT_MAX;
    if (t < vocab) {
        int c = counts[t];
        float vf; int s;
        lif_replay(v0[t], c, vf, s);
        out[t] = (s > 0) ? GAIN_DOWN : 1.0f;
        vfin = vf;
        idx = t;
    }
    sv[tid] = vfin;
    si[tid] = idx;
    __syncthreads();

    for (int r = 0; r < KWIN; ++r) {
        rv[tid] = sv[tid];
        ri[tid] = si[tid];
        __syncthreads();
        for (int stride = 128; stride > 0; stride >>= 1) {
            if (tid < stride) {
                float v2 = rv[tid + stride]; int i2 = ri[tid + stride];
                if (v2 > rv[tid] || (v2 == rv[tid] && i2 < ri[tid])) {
                    rv[tid] = v2; ri[tid] = i2;
                }
            }
            __syncthreads();
        }
        int w = ri[0];              // valid for all threads: loop ended with barrier
        if (tid == 0) {
            cand_v[blockIdx.x * KWIN + r] = rv[0];
            cand_i[blockIdx.x * KWIN + r] = w;
        }
        __syncthreads();            // everyone has read ri[0] before it is reused
        if (si[tid] == w) sv[tid] = -FLT_MAX;   // exclude winner for next round
        __syncthreads();
    }
}

// Single block: merge n_cand candidates into the global top-5, then set winners' gains.
__global__ void merge_top5(const float* __restrict__ cand_v,
                           const int* __restrict__ cand_i,
                           int n_cand,
                           float* __restrict__ out) {
    __shared__ float rv[256];
    __shared__ int   ri[256];
    __shared__ int   winners[KWIN];

    int tid = threadIdx.x;

    for (int r = 0; r < KWIN; ++r) {
        float bv = -FLT_MAX;
        int   bi = INT_MAX;
        for (int j = tid; j < n_cand; j += 256) {
            int   ci = cand_i[j];
            float cv = cand_v[j];
            bool excl = false;
            for (int q = 0; q < r; ++q) if (winners[q] == ci) excl = true;
            if (!excl && (cv > bv || (cv == bv && ci < bi))) { bv = cv; bi = ci; }
        }
        rv[tid] = bv;
        ri[tid] = bi;
        __syncthreads();
        for (int stride = 128; stride > 0; stride >>= 1) {
            if (tid < stride) {
                float v2 = rv[tid + stride]; int i2 = ri[tid + stride];
                if (v2 > rv[tid] || (v2 == rv[tid] && i2 < ri[tid])) {
                    rv[tid] = v2; ri[tid] = i2;
                }
            }
            __syncthreads();
        }
        if (tid == 0) winners[r] = ri[0];
        __syncthreads();
    }

    if (tid < KWIN) {
        int w = winners[tid];
        if (w >= 0 && w != INT_MAX) out[w] = GAIN_UP;
    }
}

extern "C" void kernel_launch(void* const* d_in, const int* in_sizes, int n_in,
                              void* d_out, int out_size, void* d_ws, size_t ws_size,
                              hipStream_t stream) {
    const int*   tok = (const int*)d_in[0];
    const float* v0  = (const float*)d_in[1];
    int n     = in_sizes[0];      // 8192
    int vocab = in_sizes[1];      // 128000 (v0 length == vocab_size)
    float* out = (float*)d_out;

    int nblocks = (vocab + 255) / 256;

    // Workspace layout: counts[vocab] int32 | cand_v[nblocks*5] f32 | cand_i[nblocks*5] i32
    int*   counts = (int*)d_ws;
    float* cand_v = (float*)((char*)d_ws + (size_t)vocab * sizeof(int));
    int*   cand_i = (int*)(cand_v + (size_t)nblocks * KWIN);

    hipMemsetAsync(counts, 0, (size_t)vocab * sizeof(int), stream);
    hist_kernel<<<(n + 255) / 256, 256, 0, stream>>>(tok, n, vocab, counts);
    gains_top5_block<<<nblocks, 256, 0, stream>>>(counts, v0, vocab, out, cand_v, cand_i);
    merge_top5<<<1, 256, 0, stream>>>(cand_v, cand_i, nblocks * KWIN, out);
}